// Round 2
// 1011.735 us; speedup vs baseline: 1.0817x; 1.0817x over previous
//
#include <hip/hip_runtime.h>
#include <math.h>

#define BB   256
#define CC   768
#define HHX  24
#define WWX  24
#define HWX  576      // H*W
#define HW4  144      // H*W/4
#define EDIM 2304     // 3*C
#define NIMG 2

// ---------------------------------------------------------------------------
// k1: per-(img,b) channel-sum heatmap, float4 loads.
// thread t: pos4 = t%144, cgroup = t/144; sums channels c ≡ cgroup (mod 4).
__global__ void k1_hm(const float* __restrict__ f1, const float* __restrict__ f2,
                      float* __restrict__ hm) {
    int blk = blockIdx.x;            // 0..511  (img*256 + b)
    int img = blk >> 8;
    int b   = blk & 255;
    const float* base = ((img == 0) ? f1 : f2) + (size_t)b * CC * HWX;
    const float4* base4 = (const float4*)base;
    int t = threadIdx.x;             // 0..575
    int pos4 = t % HW4;
    int cg   = t / HW4;              // 0..3
    float4 acc = make_float4(0.f, 0.f, 0.f, 0.f);
    #pragma unroll 8
    for (int c = cg; c < CC; c += 4) {
        float4 v = base4[(size_t)c * HW4 + pos4];
        acc.x += v.x; acc.y += v.y; acc.z += v.z; acc.w += v.w;
    }
    __shared__ float4 part[HWX];
    part[t] = acc;
    __syncthreads();
    if (t < HW4) {
        float4 a = part[t], b4 = part[t + HW4], c4 = part[t + 2 * HW4], d4 = part[t + 3 * HW4];
        float4 s;
        s.x = a.x + b4.x + c4.x + d4.x;
        s.y = a.y + b4.y + c4.y + d4.y;
        s.z = a.z + b4.z + c4.z + d4.z;
        s.w = a.w + b4.w + c4.w + d4.w;
        ((float4*)(hm + (size_t)blk * HWX))[t] = s;
    }
}

// ---------------------------------------------------------------------------
// k3: fused mask computation + pooled sums + normalize (k4 folded in).
// Block per (img,b), 512 threads (8 waves), wave handles channels c ≡ wv (mod 8).
// Channel sums stay in LDS; block then divides by counts, L2-normalizes the
// 2304-vector, writes e in-place and (img==1) the transposed copy e2t.
__global__ void k3_sums(const float* __restrict__ f1, const float* __restrict__ f2,
                        const float* __restrict__ hm, float* __restrict__ e,
                        float* __restrict__ e2t) {
    int blk = blockIdx.x;            // (img,b)
    int img = blk >> 8, b = blk & 255;
    const float* base = ((img == 0) ? f1 : f2) + (size_t)b * CC * HWX;
    int t = threadIdx.x;             // 0..511
    int lane = t & 63;
    int wv   = t >> 6;               // 0..7

    __shared__ __align__(16) float sh[HWX];
    __shared__ __align__(16) float smm[HWX];
    __shared__ __align__(16) float smn[HWX];
    __shared__ __align__(16) float esum[EDIM];   // 9216 B: [max | min | gap] sums
    __shared__ int c0, c1;

    sh[t] = hm[(size_t)blk * HWX + t];
    if (t < HWX - 512) sh[512 + t] = hm[(size_t)blk * HWX + 512 + t];
    if (t == 0) { c0 = 0; c1 = 0; }
    __syncthreads();

    // masks for positions p = t (+512)
    for (int p = t; p < HWX; p += 512) {
        int h = p / WWX, w = p % WWX;
        float v = sh[p];
        float mx = -__builtin_inff(), mn = __builtin_inff();
        #pragma unroll
        for (int dh = -1; dh <= 1; ++dh) {
            int hh = h + dh;
            if (hh < 0 || hh >= HHX) continue;
            #pragma unroll
            for (int dw = -1; dw <= 1; ++dw) {
                int ww = w + dw;
                if (ww < 0 || ww >= WWX) continue;
                float u = sh[hh * WWX + ww];
                mx = fmaxf(mx, u);
                mn = fminf(mn, u);
            }
        }
        bool corner = (p == 0) || (p == WWX - 1) || (p == (HHX - 1) * WWX) || (p == HWX - 1);
        bool ismax = (v >= mx) && !corner;
        bool ismin = (v <= mn) && !corner;
        smm[p] = ismax ? 1.f : 0.f;
        smn[p] = ismin ? 1.f : 0.f;
        if (ismax) atomicAdd(&c0, 1);
        if (ismin) atomicAdd(&c1, 1);
    }
    __syncthreads();

    // per-lane mask fragments for the vectorized layout:
    //   j0: floats 4*lane..+3, j1: floats 256+4*lane..+3, j2: float 512+lane
    float4 ma0 = ((const float4*)smm)[lane];
    float4 ma1 = ((const float4*)smm)[64 + lane];
    float  ma2 = smm[512 + lane];
    float4 mi0 = ((const float4*)smn)[lane];
    float4 mi1 = ((const float4*)smn)[64 + lane];
    float  mi2 = smn[512 + lane];

    for (int c = wv; c < CC; c += 8) {
        const float4* p4 = (const float4*)(base + (size_t)c * HWX);
        float4 v0 = p4[lane];
        float4 v1 = p4[64 + lane];
        float  v2 = (base + (size_t)c * HWX)[512 + lane];

        float s0 = v0.x + v0.y + v0.z + v0.w + v1.x + v1.y + v1.z + v1.w + v2;
        float s1 = v0.x * ma0.x + v0.y * ma0.y + v0.z * ma0.z + v0.w * ma0.w;
        s1 = fmaf(v1.x, ma1.x, s1); s1 = fmaf(v1.y, ma1.y, s1);
        s1 = fmaf(v1.z, ma1.z, s1); s1 = fmaf(v1.w, ma1.w, s1);
        s1 = fmaf(v2, ma2, s1);
        float s2 = v0.x * mi0.x + v0.y * mi0.y + v0.z * mi0.z + v0.w * mi0.w;
        s2 = fmaf(v1.x, mi1.x, s2); s2 = fmaf(v1.y, mi1.y, s2);
        s2 = fmaf(v1.z, mi1.z, s2); s2 = fmaf(v1.w, mi1.w, s2);
        s2 = fmaf(v2, mi2, s2);

        #pragma unroll
        for (int off = 32; off; off >>= 1) {
            s0 += __shfl_down(s0, off, 64);
            s1 += __shfl_down(s1, off, 64);
            s2 += __shfl_down(s2, off, 64);
        }
        if (lane == 0) {
            esum[c]          = s1;
            esum[CC + c]     = s2;
            esum[2 * CC + c] = s0;
        }
    }
    __syncthreads();

    // normalize phase (was k4): divide by counts / HW, L2-normalize row of 2304
    float invmax = 1.f / (float)c0;
    float invmin = 1.f / (float)c1;
    const float invgap = 1.f / (float)HWX;

    float val[5];
    float sq = 0.f;
    #pragma unroll
    for (int jj = 0; jj < 4; ++jj) {
        int k = t + 512 * jj;
        float d = (k < CC) ? invmax : (k < 2 * CC) ? invmin : invgap;
        float v = esum[k] * d;
        val[jj] = v;
        sq = fmaf(v, v, sq);
    }
    if (t < 256) {
        int k = 2048 + t;            // always in gap range
        float v = esum[k] * invgap;
        val[4] = v;
        sq = fmaf(v, v, sq);
    } else {
        val[4] = 0.f;
    }

    // block reduce sq over 512 threads (reuse smm as scratch; masks already
    // consumed into registers and all threads passed the post-loop barrier)
    smm[t] = sq;
    __syncthreads();
    for (int s = 256; s; s >>= 1) {
        if (t < s) smm[t] += smm[t + s];
        __syncthreads();
    }
    float rn = 1.f / sqrtf(smm[0]);

    float* eo = e + (size_t)blk * EDIM;
    #pragma unroll
    for (int jj = 0; jj < 4; ++jj) {
        int k = t + 512 * jj;
        float v = val[jj] * rn;
        eo[k] = v;
        if (img == 1) e2t[(size_t)k * BB + b] = v;
    }
    if (t < 256) {
        int k = 2048 + t;
        float v = val[4] * rn;
        eo[k] = v;
        if (img == 1) e2t[(size_t)k * BB + b] = v;
    }
}

// ---------------------------------------------------------------------------
// k5: logits[i][j] = scale * dot(e1[i], e2[j]); also writes logitsT.
// 256 blocks (one row each) x 1024 threads: 4-way k-split per column for
// 16 waves/CU of latency hiding (was 128 blocks x 4 waves = 1 wave/SIMD).
__global__ void __launch_bounds__(1024)
k5_logits(const float* __restrict__ e, const float* __restrict__ e2t,
          const float* __restrict__ scale_p, float* __restrict__ logits,
          float* __restrict__ logitsT) {
    int i = blockIdx.x;              // row 0..255
    int t = threadIdx.x;             // 0..1023
    int j = t & 255;                 // column
    int h = t >> 8;                  // k-split 0..3
    __shared__ float s1row[EDIM];
    __shared__ float part[4][256];
    for (int k = t; k < EDIM; k += 1024)
        s1row[k] = e[(size_t)i * EDIM + k];
    __syncthreads();

    float acc = 0.f;
    int k0 = h * (EDIM / 4);         // 576 k's per split
    #pragma unroll 4
    for (int kk = 0; kk < EDIM / 4; kk += 4) {
        int k = k0 + kk;
        float b0 = e2t[(size_t)(k + 0) * BB + j];
        float b1 = e2t[(size_t)(k + 1) * BB + j];
        float b2 = e2t[(size_t)(k + 2) * BB + j];
        float b3 = e2t[(size_t)(k + 3) * BB + j];
        acc = fmaf(s1row[k + 0], b0, acc);
        acc = fmaf(s1row[k + 1], b1, acc);
        acc = fmaf(s1row[k + 2], b2, acc);
        acc = fmaf(s1row[k + 3], b3, acc);
    }
    part[h][j] = acc;
    __syncthreads();
    if (h == 0) {
        float r = scale_p[0] * (part[0][j] + part[1][j] + part[2][j] + part[3][j]);
        logits[(size_t)i * BB + j] = r;
        logitsT[(size_t)j * BB + i] = r;
    }
}

// ---------------------------------------------------------------------------
// k6: one wave per LSE. g in [0,512): g<256 -> row g of logits (row LSE),
// else row g-256 of logitsT (col LSE).
__global__ void k6_lse(const float* __restrict__ logits, const float* __restrict__ logitsT,
                       float* __restrict__ lse) {
    int g = blockIdx.x * 4 + (threadIdx.x >> 6);   // 0..511
    int lane = threadIdx.x & 63;
    const float* row = (g < BB) ? (logits + (size_t)g * BB)
                                : (logitsT + (size_t)(g - BB) * BB);
    float4 v = ((const float4*)row)[lane];
    float m = fmaxf(fmaxf(v.x, v.y), fmaxf(v.z, v.w));
    #pragma unroll
    for (int off = 32; off; off >>= 1) m = fmaxf(m, __shfl_xor(m, off, 64));
    float s = expf(v.x - m) + expf(v.y - m) + expf(v.z - m) + expf(v.w - m);
    #pragma unroll
    for (int off = 32; off; off >>= 1) s += __shfl_xor(s, off, 64);
    if (lane == 0) lse[g] = m + logf(s);
}

// ---------------------------------------------------------------------------
// k7: loss = mean_i [ 0.5*(lse_row_i + lse_col_i) - diag_i ]
__global__ void k7_loss(const float* __restrict__ logits, const float* __restrict__ lse,
                        float* __restrict__ out) {
    int i = threadIdx.x;             // 0..255
    float v = 0.5f * (lse[i] + lse[BB + i]) - logits[(size_t)i * BB + i];
    __shared__ float red[256];
    red[i] = v;
    __syncthreads();
    for (int s = 128; s; s >>= 1) {
        if (i < s) red[i] += red[i + s];
        __syncthreads();
    }
    if (i == 0) out[0] = red[0] * (1.f / (float)BB);
}

// ---------------------------------------------------------------------------
extern "C" void kernel_launch(void* const* d_in, const int* in_sizes, int n_in,
                              void* d_out, int out_size, void* d_ws, size_t ws_size,
                              hipStream_t stream) {
    const float* f1 = (const float*)d_in[0];
    const float* f2 = (const float*)d_in[1];
    const float* scale_p = (const float*)d_in[2];
    float* out = (float*)d_out;

    float* ws = (float*)d_ws;
    // offsets in floats
    const size_t off_hm      = 0;                                   // 512*576
    const size_t off_sums    = off_hm      + (size_t)NIMG * BB * HWX;
    const size_t off_e2t     = off_sums    + (size_t)NIMG * BB * EDIM;
    const size_t off_logits  = off_e2t     + (size_t)EDIM * BB;
    const size_t off_logitsT = off_logits  + (size_t)BB * BB;
    const size_t off_lse     = off_logitsT + (size_t)BB * BB;

    float* hm      = ws + off_hm;
    float* sums    = ws + off_sums;   // normalized e, written by k3
    float* e2t     = ws + off_e2t;
    float* logits  = ws + off_logits;
    float* logitsT = ws + off_logitsT;
    float* lse     = ws + off_lse;

    hipLaunchKernelGGL(k1_hm,     dim3(NIMG * BB), dim3(HWX),  0, stream, f1, f2, hm);
    hipLaunchKernelGGL(k3_sums,   dim3(NIMG * BB), dim3(512),  0, stream, f1, f2, hm, sums, e2t);
    hipLaunchKernelGGL(k5_logits, dim3(BB),        dim3(1024), 0, stream, sums, e2t, scale_p, logits, logitsT);
    hipLaunchKernelGGL(k6_lse,    dim3(128),       dim3(256),  0, stream, logits, logitsT, lse);
    hipLaunchKernelGGL(k7_loss,   dim3(1),         dim3(256),  0, stream, logits, lse, out);
}